// Round 1
// baseline (570.056 us; speedup 1.0000x reference)
//
#include <hip/hip_runtime.h>

typedef unsigned short u16;
typedef unsigned int u32;
typedef __bf16 bf16x8 __attribute__((ext_vector_type(8)));
typedef float f32x4 __attribute__((ext_vector_type(4)));

__device__ __forceinline__ u16 f2b(float f) {
  u32 u = __float_as_uint(f);
  u32 r = (u + 0x7fffu + ((u >> 16) & 1u)) >> 16;
  return (u16)r;
}
__device__ __forceinline__ float b2f(u16 v) {
  return __uint_as_float(((u32)v) << 16);
}

// ---------------- fp32 -> bf16 cast ----------------
__global__ __launch_bounds__(256) void convert_f32_bf16(
    const float4* __restrict__ in, ushort4* __restrict__ out, int n4) {
  int i = blockIdx.x * 256 + threadIdx.x;
  if (i >= n4) return;
  float4 f = in[i];
  ushort4 o;
  o.x = f2b(f.x); o.y = f2b(f.y); o.z = f2b(f.z); o.w = f2b(f.w);
  out[i] = o;
}

// ---------------- GEMM: C[M,N] = A[M,K] * B[N,K]^T + bias ----------------
// m97 structure: 128x128 tile, BK=32, 4 waves (2x2 of 64x64), 16x16x32 bf16 MFMA,
// global_load_lds width=16 staging.
template <int OUT_BF16>
__global__ __launch_bounds__(256) void gemm_bt(
    const u16* __restrict__ A, const u16* __restrict__ B,
    const float* __restrict__ bias, void* __restrict__ Cv,
    int M, int N, int K) {
  __shared__ __align__(16) u16 As[128 * 32];
  __shared__ __align__(16) u16 Bs[128 * 32];
  const int tid = threadIdx.x;
  const int lane = tid & 63;
  const int wave = tid >> 6;
  const int m0 = blockIdx.y * 128;
  const int n0 = blockIdx.x * 128;
  const int wm = (wave & 1) * 64;
  const int wn = (wave >> 1) * 64;
  f32x4 acc[4][4] = {};

  const int srow0 = wave * 32 + (lane >> 2);  // staging row (first of 2 chunks)
  const int scb = (lane & 3) * 16;            // byte offset within 64B k-row
  const int fr = lane & 15;                   // frag row (m or n)
  const int fko = (lane >> 4) * 8;            // frag k offset (elements)

  const int kiters = K >> 5;
  for (int kt = 0; kt < kiters; ++kt) {
    const int k0 = kt << 5;
    __syncthreads();
    {
      const char* gA0 = (const char*)A + ((size_t)(m0 + srow0) * K + k0) * 2 + scb;
      const char* gA1 = gA0 + (size_t)16 * K * 2;
      const char* gB0 = (const char*)B + ((size_t)(n0 + srow0) * K + k0) * 2 + scb;
      const char* gB1 = gB0 + (size_t)16 * K * 2;
      __builtin_amdgcn_global_load_lds(
          (__attribute__((address_space(1))) void*)gA0,
          (__attribute__((address_space(3))) void*)(As + (wave * 2 + 0) * 512), 16, 0, 0);
      __builtin_amdgcn_global_load_lds(
          (__attribute__((address_space(1))) void*)gA1,
          (__attribute__((address_space(3))) void*)(As + (wave * 2 + 1) * 512), 16, 0, 0);
      __builtin_amdgcn_global_load_lds(
          (__attribute__((address_space(1))) void*)gB0,
          (__attribute__((address_space(3))) void*)(Bs + (wave * 2 + 0) * 512), 16, 0, 0);
      __builtin_amdgcn_global_load_lds(
          (__attribute__((address_space(1))) void*)gB1,
          (__attribute__((address_space(3))) void*)(Bs + (wave * 2 + 1) * 512), 16, 0, 0);
    }
    __syncthreads();
    bf16x8 aF[4], bF[4];
#pragma unroll
    for (int mi = 0; mi < 4; ++mi)
      __builtin_memcpy(&aF[mi], &As[(wm + mi * 16 + fr) * 32 + fko], 16);
#pragma unroll
    for (int ni = 0; ni < 4; ++ni)
      __builtin_memcpy(&bF[ni], &Bs[(wn + ni * 16 + fr) * 32 + fko], 16);
#pragma unroll
    for (int mi = 0; mi < 4; ++mi)
#pragma unroll
      for (int ni = 0; ni < 4; ++ni)
        acc[mi][ni] = __builtin_amdgcn_mfma_f32_16x16x32_bf16(aF[mi], bF[ni], acc[mi][ni], 0, 0, 0);
  }
  // epilogue: C/D layout col=lane&15, row=(lane>>4)*4+i (m89-verified)
  const int rq = (lane >> 4) * 4;
  const int cq = lane & 15;
#pragma unroll
  for (int mi = 0; mi < 4; ++mi) {
#pragma unroll
    for (int ni = 0; ni < 4; ++ni) {
      int col = n0 + wn + ni * 16 + cq;
      float bs = bias[col];
#pragma unroll
      for (int i = 0; i < 4; ++i) {
        int row = m0 + wm + mi * 16 + rq + i;
        float v = acc[mi][ni][i] + bs;
        if (OUT_BF16)
          ((u16*)Cv)[(size_t)row * N + col] = f2b(v);
        else
          ((float*)Cv)[(size_t)row * N + col] = v;
      }
    }
  }
}

// ---------------- RoPE + split + head reshape ----------------
// qkv: (B*L, 6144) bf16 -> qh/kh/vh: (B*H, L, 128) bf16, rope on q,k
__global__ __launch_bounds__(256) void rope_reshape(
    const u16* __restrict__ qkv, u16* __restrict__ qh,
    u16* __restrict__ kh, u16* __restrict__ vh) {
  int idx = blockIdx.x * 256 + threadIdx.x;  // B*L*H*64 = 4194304 threads
  int i = idx & 63;
  int h = (idx >> 6) & 15;
  int l = (idx >> 10) & 2047;
  int b = idx >> 21;
  const u16* row = qkv + ((size_t)(b * 2048 + l)) * 6144;
  int off = h * 128 + i;
  float q1 = b2f(row[off]), q2 = b2f(row[off + 64]);
  float k1 = b2f(row[2048 + off]), k2 = b2f(row[2048 + off + 64]);
  float inv = powf(10000.0f, -(float)i * (1.0f / 64.0f));
  float ang = (float)l * inv;
  float s, c;
  sincosf(ang, &s, &c);
  size_t o = ((size_t)(b * 16 + h) * 2048 + l) * 128;
  qh[o + i] = f2b(q1 * c - q2 * s);
  qh[o + 64 + i] = f2b(q2 * c + q1 * s);
  kh[o + i] = f2b(k1 * c - k2 * s);
  kh[o + 64 + i] = f2b(k2 * c + k1 * s);
  vh[o + i] = row[4096 + off];
  vh[o + 64 + i] = row[4096 + off + 64];
}

// ---------------- causal flash attention ----------------
// grid: (qtile=16, bh=32). block 256 = 4 waves, BM=128 (32 rows/wave), BN=64, d=128.
__global__ __launch_bounds__(256) void attn_flash(
    const u16* __restrict__ qh, const u16* __restrict__ kh,
    const u16* __restrict__ vh, u16* __restrict__ oh) {
  __shared__ __align__(16) u16 Ks[64 * 136];   // [pos][d], pad 136
  __shared__ __align__(16) u16 Vt[128 * 72];   // [d][pos], pad 72
  __shared__ __align__(16) u16 Ps[128 * 72];   // [qrow][pos], pad 72
  const int tid = threadIdx.x;
  const int lane = tid & 63;
  const int wave = tid >> 6;
  const int qt = blockIdx.x;
  const int bh = blockIdx.y;
  const int b = bh >> 4;
  const int h = bh & 15;
  const float scale = 0.08838834764831845f;  // 1/sqrt(128)
  const int rq = (lane >> 4) * 4;  // C-layout row base
  const int cq = lane & 15;        // C-layout col
  const int fr = lane & 15;        // A/B frag row
  const int fko = (lane >> 4) * 8; // frag k offset

  // Q fragments held in registers for the whole block (reused across K-tiles)
  bf16x8 qf[2][4];
  const size_t qbase = (size_t)bh * 2048 + qt * 128 + wave * 32;
#pragma unroll
  for (int mi = 0; mi < 2; ++mi)
#pragma unroll
    for (int ks = 0; ks < 4; ++ks)
      __builtin_memcpy(&qf[mi][ks], qh + (qbase + mi * 16 + fr) * 128 + ks * 32 + fko, 16);

  f32x4 o[2][8] = {};
  float mrow[2][4], lrow[2][4];
#pragma unroll
  for (int mi = 0; mi < 2; ++mi)
#pragma unroll
    for (int i = 0; i < 4; ++i) { mrow[mi][i] = -3.0e38f; lrow[mi][i] = 0.0f; }

  const int ktiles = 2 * qt + 2;  // causal: cols up to qt*128+127
  for (int kt = 0; kt < ktiles; ++kt) {
    __syncthreads();
    const size_t kvbase = (size_t)bh * 2048 + kt * 64;
    // stage K tile [64][128] -> Ks (coalesced 16B)
#pragma unroll
    for (int c = 0; c < 4; ++c) {
      int idx = c * 256 + tid;
      int row = idx >> 4;
      int col8 = (idx & 15) * 8;
      uint4 d = *(const uint4*)(kh + (kvbase + row) * 128 + col8);
      *(uint4*)&Ks[row * 136 + col8] = d;
    }
    // stage V transposed -> Vt[d][pos] (conflict-free scalar writes)
#pragma unroll
    for (int c = 0; c < 4; ++c) {
      int idx = c * 256 + tid;
      int d8 = (idx >> 6) * 8;
      int pos = idx & 63;
      uint4 dv = *(const uint4*)(vh + (kvbase + pos) * 128 + d8);
      const u16* pv = (const u16*)&dv;
#pragma unroll
      for (int j = 0; j < 8; ++j) Vt[(d8 + j) * 72 + pos] = pv[j];
    }
    __syncthreads();

    // S = Q K^T  (fp32 acc), wave owns 32 q-rows x 64 cols
    f32x4 S[2][4] = {};
#pragma unroll
    for (int ks = 0; ks < 4; ++ks) {
      bf16x8 kf[4];
#pragma unroll
      for (int ni = 0; ni < 4; ++ni)
        __builtin_memcpy(&kf[ni], &Ks[(ni * 16 + fr) * 136 + ks * 32 + fko], 16);
#pragma unroll
      for (int mi = 0; mi < 2; ++mi)
#pragma unroll
        for (int ni = 0; ni < 4; ++ni)
          S[mi][ni] = __builtin_amdgcn_mfma_f32_16x16x32_bf16(qf[mi][ks], kf[ni], S[mi][ni], 0, 0, 0);
    }

    // scale + causal mask (only last 2 tiles can cross diagonal)
    const int row0 = qt * 128 + wave * 32;
    const bool need_mask = (kt >= 2 * qt);
#pragma unroll
    for (int mi = 0; mi < 2; ++mi)
#pragma unroll
      for (int ni = 0; ni < 4; ++ni)
#pragma unroll
        for (int i = 0; i < 4; ++i) {
          float s = S[mi][ni][i] * scale;
          if (need_mask) {
            int r = row0 + mi * 16 + rq + i;
            int cg = kt * 64 + ni * 16 + cq;
            if (cg > r) s = -3.0e38f;
          }
          S[mi][ni][i] = s;
        }

    // online softmax per q-row (rows live in 16-lane groups)
#pragma unroll
    for (int mi = 0; mi < 2; ++mi)
#pragma unroll
      for (int i = 0; i < 4; ++i) {
        float mx = fmaxf(fmaxf(S[mi][0][i], S[mi][1][i]), fmaxf(S[mi][2][i], S[mi][3][i]));
        mx = fmaxf(mx, __shfl_xor(mx, 1));
        mx = fmaxf(mx, __shfl_xor(mx, 2));
        mx = fmaxf(mx, __shfl_xor(mx, 4));
        mx = fmaxf(mx, __shfl_xor(mx, 8));
        float mnew = fmaxf(mrow[mi][i], mx);
        float alpha = __expf(mrow[mi][i] - mnew);
        mrow[mi][i] = mnew;
        float rs = 0.0f;
#pragma unroll
        for (int ni = 0; ni < 4; ++ni) {
          float p = __expf(S[mi][ni][i] - mnew);
          S[mi][ni][i] = p;
          rs += p;
        }
        rs += __shfl_xor(rs, 1);
        rs += __shfl_xor(rs, 2);
        rs += __shfl_xor(rs, 4);
        rs += __shfl_xor(rs, 8);
        lrow[mi][i] = lrow[mi][i] * alpha + rs;
#pragma unroll
        for (int ni = 0; ni < 8; ++ni) o[mi][ni][i] *= alpha;
      }

    // P (C-layout) -> LDS -> A-layout frags
#pragma unroll
    for (int mi = 0; mi < 2; ++mi)
#pragma unroll
      for (int ni = 0; ni < 4; ++ni)
#pragma unroll
        for (int i = 0; i < 4; ++i)
          Ps[(wave * 32 + mi * 16 + rq + i) * 72 + ni * 16 + cq] = f2b(S[mi][ni][i]);
    __syncthreads();

    // O += P V
#pragma unroll
    for (int ks = 0; ks < 2; ++ks) {
      bf16x8 pf[2];
#pragma unroll
      for (int mi = 0; mi < 2; ++mi)
        __builtin_memcpy(&pf[mi], &Ps[(wave * 32 + mi * 16 + fr) * 72 + ks * 32 + fko], 16);
#pragma unroll
      for (int ni = 0; ni < 8; ++ni) {
        bf16x8 vf;
        __builtin_memcpy(&vf, &Vt[(ni * 16 + fr) * 72 + ks * 32 + fko], 16);
#pragma unroll
        for (int mi = 0; mi < 2; ++mi)
          o[mi][ni] = __builtin_amdgcn_mfma_f32_16x16x32_bf16(pf[mi], vf, o[mi][ni], 0, 0, 0);
      }
    }
  }

  // normalize + store in (B, L, H*128) order (feeds GEMM2 directly)
#pragma unroll
  for (int mi = 0; mi < 2; ++mi)
#pragma unroll
    for (int i = 0; i < 4; ++i) {
      float inv = 1.0f / lrow[mi][i];
      int row_l = qt * 128 + wave * 32 + mi * 16 + rq + i;
      size_t base = ((size_t)b * 2048 + row_l) * 2048 + (size_t)h * 128;
#pragma unroll
      for (int ni = 0; ni < 8; ++ni)
        oh[base + ni * 16 + cq] = f2b(o[mi][ni][i] * inv);
    }
}

extern "C" void kernel_launch(void* const* d_in, const int* in_sizes, int n_in,
                              void* d_out, int out_size, void* d_ws, size_t ws_size,
                              hipStream_t stream) {
  (void)in_sizes; (void)n_in; (void)out_size; (void)ws_size;
  const float* query = (const float*)d_in[0];
  const float* W_qkv = (const float*)d_in[1];
  const float* b_qkv = (const float*)d_in[2];
  const float* W_out = (const float*)d_in[3];
  const float* b_out = (const float*)d_in[4];
  float* out = (float*)d_out;
  char* ws = (char*)d_ws;

  // workspace layout (160 MB total)
  u16* Abf  = (u16*)(ws + 0);                    // 16 MB  query bf16 (4096x2048)
  u16* W1bf = (u16*)(ws + (size_t)16777216);     // 24 MB  W_qkv bf16 (6144x2048)
  u16* W2bf = (u16*)(ws + (size_t)41943040);     //  8 MB  W_out bf16 (2048x2048)
  u16* QKV  = (u16*)(ws + (size_t)50331648);     // 48 MB  qkv bf16 (4096x6144)
  u16* qhp  = (u16*)(ws + (size_t)100663296);    // 16 MB  (B*H,L,128)
  u16* khp  = (u16*)(ws + (size_t)117440512);    // 16 MB
  u16* vhp  = (u16*)(ws + (size_t)134217728);    // 16 MB
  u16* ohp  = (u16*)(ws + (size_t)150994944);    // 16 MB  attn out (B,L,2048)

  convert_f32_bf16<<<8192, 256, 0, stream>>>((const float4*)query, (ushort4*)Abf, 2097152);
  convert_f32_bf16<<<12288, 256, 0, stream>>>((const float4*)W_qkv, (ushort4*)W1bf, 3145728);
  convert_f32_bf16<<<4096, 256, 0, stream>>>((const float4*)W_out, (ushort4*)W2bf, 1048576);
  gemm_bt<1><<<dim3(48, 32), 256, 0, stream>>>(Abf, W1bf, b_qkv, (void*)QKV, 4096, 6144, 2048);
  rope_reshape<<<16384, 256, 0, stream>>>(QKV, qhp, khp, vhp);
  attn_flash<<<dim3(16, 32), 256, 0, stream>>>(qhp, khp, vhp, ohp);
  gemm_bt<0><<<dim3(16, 32), 256, 0, stream>>>(ohp, W2bf, b_out, (void*)out, 4096, 2048, 2048);
}

// Round 2
// 465.803 us; speedup vs baseline: 1.2238x; 1.2238x over previous
//
#include <hip/hip_runtime.h>

typedef unsigned short u16;
typedef unsigned int u32;
typedef __bf16 bf16x8 __attribute__((ext_vector_type(8)));
typedef float f32x4 __attribute__((ext_vector_type(4)));

__device__ __forceinline__ u16 f2b(float f) {
  u32 u = __float_as_uint(f);
  u32 r = (u + 0x7fffu + ((u >> 16) & 1u)) >> 16;
  return (u16)r;
}
__device__ __forceinline__ float b2f(u16 v) {
  return __uint_as_float(((u32)v) << 16);
}

// ---------------- fp32 -> bf16 cast ----------------
__global__ __launch_bounds__(256) void convert_f32_bf16(
    const float4* __restrict__ in, ushort4* __restrict__ out, int n4) {
  int i = blockIdx.x * 256 + threadIdx.x;
  if (i >= n4) return;
  float4 f = in[i];
  ushort4 o;
  o.x = f2b(f.x); o.y = f2b(f.y); o.z = f2b(f.z); o.w = f2b(f.w);
  out[i] = o;
}

// ---------------- GEMM: C[M,N] = A[M,K] * B[N,K]^T + bias ----------------
template <int OUT_BF16>
__global__ __launch_bounds__(256) void gemm_bt(
    const u16* __restrict__ A, const u16* __restrict__ B,
    const float* __restrict__ bias, void* __restrict__ Cv,
    int M, int N, int K) {
  __shared__ __align__(16) u16 As[128 * 32];
  __shared__ __align__(16) u16 Bs[128 * 32];
  const int tid = threadIdx.x;
  const int lane = tid & 63;
  const int wave = tid >> 6;
  const int m0 = blockIdx.y * 128;
  const int n0 = blockIdx.x * 128;
  const int wm = (wave & 1) * 64;
  const int wn = (wave >> 1) * 64;
  f32x4 acc[4][4] = {};

  const int srow0 = wave * 32 + (lane >> 2);
  const int scb = (lane & 3) * 16;
  const int fr = lane & 15;
  const int fko = (lane >> 4) * 8;

  const int kiters = K >> 5;
  for (int kt = 0; kt < kiters; ++kt) {
    const int k0 = kt << 5;
    __syncthreads();
    {
      const char* gA0 = (const char*)A + ((size_t)(m0 + srow0) * K + k0) * 2 + scb;
      const char* gA1 = gA0 + (size_t)16 * K * 2;
      const char* gB0 = (const char*)B + ((size_t)(n0 + srow0) * K + k0) * 2 + scb;
      const char* gB1 = gB0 + (size_t)16 * K * 2;
      __builtin_amdgcn_global_load_lds(
          (__attribute__((address_space(1))) void*)gA0,
          (__attribute__((address_space(3))) void*)(As + (wave * 2 + 0) * 512), 16, 0, 0);
      __builtin_amdgcn_global_load_lds(
          (__attribute__((address_space(1))) void*)gA1,
          (__attribute__((address_space(3))) void*)(As + (wave * 2 + 1) * 512), 16, 0, 0);
      __builtin_amdgcn_global_load_lds(
          (__attribute__((address_space(1))) void*)gB0,
          (__attribute__((address_space(3))) void*)(Bs + (wave * 2 + 0) * 512), 16, 0, 0);
      __builtin_amdgcn_global_load_lds(
          (__attribute__((address_space(1))) void*)gB1,
          (__attribute__((address_space(3))) void*)(Bs + (wave * 2 + 1) * 512), 16, 0, 0);
    }
    __syncthreads();
    bf16x8 aF[4], bF[4];
#pragma unroll
    for (int mi = 0; mi < 4; ++mi)
      __builtin_memcpy(&aF[mi], &As[(wm + mi * 16 + fr) * 32 + fko], 16);
#pragma unroll
    for (int ni = 0; ni < 4; ++ni)
      __builtin_memcpy(&bF[ni], &Bs[(wn + ni * 16 + fr) * 32 + fko], 16);
#pragma unroll
    for (int mi = 0; mi < 4; ++mi)
#pragma unroll
      for (int ni = 0; ni < 4; ++ni)
        acc[mi][ni] = __builtin_amdgcn_mfma_f32_16x16x32_bf16(aF[mi], bF[ni], acc[mi][ni], 0, 0, 0);
  }
  const int rq = (lane >> 4) * 4;
  const int cq = lane & 15;
#pragma unroll
  for (int mi = 0; mi < 4; ++mi) {
#pragma unroll
    for (int ni = 0; ni < 4; ++ni) {
      int col = n0 + wn + ni * 16 + cq;
      float bs = bias[col];
#pragma unroll
      for (int i = 0; i < 4; ++i) {
        int row = m0 + wm + mi * 16 + rq + i;
        float v = acc[mi][ni][i] + bs;
        if (OUT_BF16)
          ((u16*)Cv)[(size_t)row * N + col] = f2b(v);
        else
          ((float*)Cv)[(size_t)row * N + col] = v;
      }
    }
  }
}

// ---------------- RoPE on q,k (q pre-scaled by 1/sqrt(d)) ----------------
__global__ __launch_bounds__(256) void rope_reshape(
    const u16* __restrict__ qkv, u16* __restrict__ qh, u16* __restrict__ kh) {
  int idx = blockIdx.x * 256 + threadIdx.x;  // B*L*H*64 threads
  int i = idx & 63;
  int h = (idx >> 6) & 15;
  int l = (idx >> 10) & 2047;
  int b = idx >> 21;
  const u16* row = qkv + ((size_t)(b * 2048 + l)) * 6144;
  int off = h * 128 + i;
  float q1 = b2f(row[off]), q2 = b2f(row[off + 64]);
  float k1 = b2f(row[2048 + off]), k2 = b2f(row[2048 + off + 64]);
  float inv = exp2f(-(float)i * 0.20762050593046869f);  // log2(10000)/64
  float ang = (float)l * inv;
  float s, c;
  sincosf(ang, &s, &c);
  size_t o = ((size_t)(b * 16 + h) * 2048 + l) * 128;
  const float qs = 0.08838834764831845f;  // 1/sqrt(128) folded into q
  qh[o + i]      = f2b((q1 * c - q2 * s) * qs);
  qh[o + 64 + i] = f2b((q2 * c + q1 * s) * qs);
  kh[o + i]      = f2b(k1 * c - k2 * s);
  kh[o + 64 + i] = f2b(k2 * c + k1 * s);
}

// ---------------- V transpose: qkv v-slice -> vhT[(b,h), d, L] ----------------
__global__ __launch_bounds__(256) void transpose_v(
    const u16* __restrict__ qkv, u16* __restrict__ vhT) {
  __shared__ u16 Ts[64 * 65];
  const int tid = threadIdx.x;
  const int lt = blockIdx.x;   // 0..31  l tile
  const int dh = blockIdx.y;   // 0..1   d half
  const int bh = blockIdx.z;   // 0..31
  const int b = bh >> 4, h = bh & 15;
  const int l0 = lt * 64, d0 = dh * 64;
#pragma unroll
  for (int it = 0; it < 16; ++it) {
    int idx = it * 256 + tid;
    int l = idx >> 6, d = idx & 63;
    Ts[l * 65 + d] =
        qkv[((size_t)(b * 2048 + l0 + l)) * 6144 + 4096 + h * 128 + d0 + d];
  }
  __syncthreads();
#pragma unroll
  for (int it = 0; it < 16; ++it) {
    int idx = it * 256 + tid;
    int d = idx >> 6, l = idx & 63;
    vhT[((size_t)bh * 128 + d0 + d) * 2048 + l0 + l] = Ts[l * 65 + d];
  }
}

// ---------------- causal flash attention, S^T orientation ----------------
// grid (16 pairs, 32 bh), 4 waves. Block owns q-subtiles (p, 31-p), 64 rows each.
// Wave w: 16 q of subtile A + 16 q of subtile B (two MFMA n-tiles), sharing staged K/V.
// S^T = K.Q^T so softmax stats live per q = lane&15; O^T = V^T.P^T keeps that
// orientation -> alpha/l rescale needs no cross-lane transport.
__global__ __launch_bounds__(256, 2) void attn_flash(
    const u16* __restrict__ qh, const u16* __restrict__ kh,
    const u16* __restrict__ vhT, u16* __restrict__ oh) {
  __shared__ __align__(16) u16 Ks[64 * 136];   // [kpos][d]
  __shared__ __align__(16) u16 Vt[128 * 72];   // [d][kpos]
  __shared__ __align__(16) u16 Ps[128 * 72];   // [q_local][kpos], wave-private rows
  const int tid = threadIdx.x;
  const int lane = tid & 63;
  const int w = tid >> 6;
  const int cq = lane & 15;
  const int g = lane >> 4;
  const int p = blockIdx.x;
  const int bh = blockIdx.y;
  const int b = bh >> 4, h = bh & 15;
  const int ktiles = 32 - p;
  int q0s[2];
  q0s[0] = p * 64;
  q0s[1] = (31 - p) * 64;

  // Q fragments (B-operand layout): lane holds Q[q = base+cq][d = ks*32+g*8+j]
  bf16x8 qf[2][4];
#pragma unroll
  for (int s = 0; s < 2; ++s) {
    const u16* qp = qh + ((size_t)bh * 2048 + q0s[s] + w * 16 + cq) * 128 + g * 8;
#pragma unroll
    for (int ks = 0; ks < 4; ++ks)
      __builtin_memcpy(&qf[s][ks], qp + ks * 32, 16);
  }

  f32x4 o[2][8] = {};  // O^T: [subtile][d-tile], col = q = cq
  float mrow[2] = {-1e30f, -1e30f};
  float lrow[2] = {0.0f, 0.0f};

  for (int kt = 0; kt < ktiles; ++kt) {
    __syncthreads();
    {
      const size_t kvb = (size_t)bh * 2048 + (size_t)kt * 64;
#pragma unroll
      for (int c = 0; c < 4; ++c) {
        int idx = c * 256 + tid;
        int row = idx >> 4, col8 = (idx & 15) * 8;
        uint4 d = *(const uint4*)(kh + (kvb + row) * 128 + col8);
        *(uint4*)&Ks[row * 136 + col8] = d;
      }
#pragma unroll
      for (int c = 0; c < 4; ++c) {
        int idx = c * 256 + tid;
        int dd = idx >> 3, p8 = (idx & 7) * 8;
        uint4 d = *(const uint4*)(vhT + ((size_t)bh * 128 + dd) * 2048 + kt * 64 + p8);
        *(uint4*)&Vt[dd * 72 + p8] = d;
      }
    }
    __syncthreads();

    const bool nA = (kt <= p);  // subtile A still active (block-uniform)
    // S^T = K.Q^T : rows = kpos (4 m-tiles), cols = q (one n-tile per subtile)
    f32x4 S[4][2] = {};
#pragma unroll
    for (int ks = 0; ks < 4; ++ks) {
#pragma unroll
      for (int mt = 0; mt < 4; ++mt) {
        bf16x8 kf;
        __builtin_memcpy(&kf, &Ks[(mt * 16 + cq) * 136 + ks * 32 + g * 8], 16);
        if (nA)
          S[mt][0] = __builtin_amdgcn_mfma_f32_16x16x32_bf16(kf, qf[0][ks], S[mt][0], 0, 0, 0);
        S[mt][1] = __builtin_amdgcn_mfma_f32_16x16x32_bf16(kf, qf[1][ks], S[mt][1], 0, 0, 0);
      }
    }

    // online softmax per subtile; q = cq for every lane
#pragma unroll
    for (int s = 0; s < 2; ++s) {
      if (s == 0 && !nA) continue;
      const int dtile = s ? (ktiles - 1) : p;
      if (kt == dtile) {  // diagonal tile: causal mask kpos > q
        const int qg = q0s[s] + w * 16 + cq;
#pragma unroll
        for (int mt = 0; mt < 4; ++mt)
#pragma unroll
          for (int i = 0; i < 4; ++i)
            if (kt * 64 + mt * 16 + g * 4 + i > qg) S[mt][s][i] = -1e30f;
      }
      float mx = S[0][s][0];
#pragma unroll
      for (int mt = 0; mt < 4; ++mt)
#pragma unroll
        for (int i = 0; i < 4; ++i) mx = fmaxf(mx, S[mt][s][i]);
      mx = fmaxf(mx, __shfl_xor(mx, 16));
      mx = fmaxf(mx, __shfl_xor(mx, 32));
      float mnew = fmaxf(mrow[s], mx);
      float al = __expf(mrow[s] - mnew);
      mrow[s] = mnew;
      float rs = 0.0f;
#pragma unroll
      for (int mt = 0; mt < 4; ++mt) {
        float e0 = __expf(S[mt][s][0] - mnew);
        float e1 = __expf(S[mt][s][1] - mnew);
        float e2 = __expf(S[mt][s][2] - mnew);
        float e3 = __expf(S[mt][s][3] - mnew);
        rs += (e0 + e1) + (e2 + e3);
        ushort4 pk;
        pk.x = f2b(e0); pk.y = f2b(e1); pk.z = f2b(e2); pk.w = f2b(e3);
        // P^T packed along kpos -> Ps[q][k] (wave-private rows; no barrier needed)
        *(ushort4*)&Ps[(s * 64 + w * 16 + cq) * 72 + mt * 16 + g * 4] = pk;
      }
      rs += __shfl_xor(rs, 16);
      rs += __shfl_xor(rs, 32);
      lrow[s] = lrow[s] * al + rs;
#pragma unroll
      for (int dmt = 0; dmt < 8; ++dmt) {
        o[s][dmt][0] *= al; o[s][dmt][1] *= al;
        o[s][dmt][2] *= al; o[s][dmt][3] *= al;
      }
    }

    // O^T += V^T . P^T
#pragma unroll
    for (int ks = 0; ks < 2; ++ks) {
      bf16x8 pf0, pf1;
      if (nA) __builtin_memcpy(&pf0, &Ps[(w * 16 + cq) * 72 + ks * 32 + g * 8], 16);
      __builtin_memcpy(&pf1, &Ps[(64 + w * 16 + cq) * 72 + ks * 32 + g * 8], 16);
#pragma unroll
      for (int dmt = 0; dmt < 8; ++dmt) {
        bf16x8 vf;
        __builtin_memcpy(&vf, &Vt[(dmt * 16 + cq) * 72 + ks * 32 + g * 8], 16);
        if (nA)
          o[0][dmt] = __builtin_amdgcn_mfma_f32_16x16x32_bf16(vf, pf0, o[0][dmt], 0, 0, 0);
        o[1][dmt] = __builtin_amdgcn_mfma_f32_16x16x32_bf16(vf, pf1, o[1][dmt], 0, 0, 0);
      }
    }
  }

  // epilogue: O^T element (d = dmt*16+g*4+i, q = cq) -> oh[b, q, h*128+d] (bf16)
#pragma unroll
  for (int s = 0; s < 2; ++s) {
    float inv = 1.0f / lrow[s];
    int qg = q0s[s] + w * 16 + cq;
    size_t base = ((size_t)(b * 2048 + qg)) * 2048 + h * 128;
#pragma unroll
    for (int dmt = 0; dmt < 8; ++dmt) {
      ushort4 t;
      t.x = f2b(o[s][dmt][0] * inv);
      t.y = f2b(o[s][dmt][1] * inv);
      t.z = f2b(o[s][dmt][2] * inv);
      t.w = f2b(o[s][dmt][3] * inv);
      *(ushort4*)(oh + base + dmt * 16 + g * 4) = t;
    }
  }
}

extern "C" void kernel_launch(void* const* d_in, const int* in_sizes, int n_in,
                              void* d_out, int out_size, void* d_ws, size_t ws_size,
                              hipStream_t stream) {
  (void)in_sizes; (void)n_in; (void)out_size; (void)ws_size;
  const float* query = (const float*)d_in[0];
  const float* W_qkv = (const float*)d_in[1];
  const float* b_qkv = (const float*)d_in[2];
  const float* W_out = (const float*)d_in[3];
  const float* b_out = (const float*)d_in[4];
  float* out = (float*)d_out;
  char* ws = (char*)d_ws;

  u16* Abf  = (u16*)(ws + 0);                    // 16 MB  query bf16 (4096x2048)
  u16* W1bf = (u16*)(ws + (size_t)16777216);     // 24 MB  W_qkv bf16 (6144x2048)
  u16* W2bf = (u16*)(ws + (size_t)41943040);     //  8 MB  W_out bf16 (2048x2048)
  u16* QKV  = (u16*)(ws + (size_t)50331648);     // 48 MB  qkv bf16 (4096x6144)
  u16* qhp  = (u16*)(ws + (size_t)100663296);    // 16 MB  (B*H,L,128), pre-scaled
  u16* khp  = (u16*)(ws + (size_t)117440512);    // 16 MB  (B*H,L,128)
  u16* vhT  = (u16*)(ws + (size_t)134217728);    // 16 MB  (B*H,128,L) transposed
  u16* ohp  = (u16*)(ws + (size_t)150994944);    // 16 MB  attn out (B,L,2048)

  convert_f32_bf16<<<8192, 256, 0, stream>>>((const float4*)query, (ushort4*)Abf, 2097152);
  convert_f32_bf16<<<12288, 256, 0, stream>>>((const float4*)W_qkv, (ushort4*)W1bf, 3145728);
  convert_f32_bf16<<<4096, 256, 0, stream>>>((const float4*)W_out, (ushort4*)W2bf, 1048576);
  gemm_bt<1><<<dim3(48, 32), 256, 0, stream>>>(Abf, W1bf, b_qkv, (void*)QKV, 4096, 6144, 2048);
  rope_reshape<<<16384, 256, 0, stream>>>(QKV, qhp, khp);
  transpose_v<<<dim3(32, 2, 32), 256, 0, stream>>>(QKV, vhT);
  attn_flash<<<dim3(16, 32), 256, 0, stream>>>(qhp, khp, vhT, ohp);
  gemm_bt<0><<<dim3(16, 32), 256, 0, stream>>>(ohp, W2bf, b_out, (void*)out, 4096, 2048, 2048);
}

// Round 3
// 413.660 us; speedup vs baseline: 1.3781x; 1.1261x over previous
//
#include <hip/hip_runtime.h>

typedef unsigned short u16;
typedef unsigned int u32;
typedef __bf16 bf16x8 __attribute__((ext_vector_type(8)));
typedef float f32x4 __attribute__((ext_vector_type(4)));

__device__ __forceinline__ u16 f2b(float f) {
  u32 u = __float_as_uint(f);
  u32 r = (u + 0x7fffu + ((u >> 16) & 1u)) >> 16;
  return (u16)r;
}
__device__ __forceinline__ float b2f(u16 v) {
  return __uint_as_float(((u32)v) << 16);
}

// ---------------- fp32 -> bf16 cast ----------------
__global__ __launch_bounds__(256) void convert_f32_bf16(
    const float4* __restrict__ in, ushort4* __restrict__ out, int n4) {
  int i = blockIdx.x * 256 + threadIdx.x;
  if (i >= n4) return;
  float4 f = in[i];
  ushort4 o;
  o.x = f2b(f.x); o.y = f2b(f.y); o.z = f2b(f.z); o.w = f2b(f.w);
  out[i] = o;
}

// ---------------- GEMM: C[M,N] = A[M,K] * B[N,K]^T + bias ----------------
// 128x128 tile, BK=32, 16x16x32 MFMA, global_load_lds staging with XOR-swizzled
// LDS layout: slot f = (chunk + (row>>1)) & 3  (chunk = 16B column chunk).
// Kills the 8-way ds_read_b128 bank conflicts of the unswizzled stride-32 layout.
template <int OUT_BF16>
__global__ __launch_bounds__(256) void gemm_bt(
    const u16* __restrict__ A, const u16* __restrict__ B,
    const float* __restrict__ bias, void* __restrict__ Cv,
    int M, int N, int K) {
  __shared__ __align__(16) u16 As[128 * 32];
  __shared__ __align__(16) u16 Bs[128 * 32];
  const int tid = threadIdx.x;
  const int lane = tid & 63;
  const int wave = tid >> 6;
  const int m0 = blockIdx.y * 128;
  const int n0 = blockIdx.x * 128;
  const int wm = (wave & 1) * 64;
  const int wn = (wave >> 1) * 64;
  f32x4 acc[4][4] = {};

  // staging: lane l covers (row = l>>2, slot = l&3); fetch global chunk
  // c' = (slot - (row>>1)) & 3 so that slot f holds chunk (f + row>>1)&3... inverse.
  const int sr = lane >> 2, sc = lane & 3;
  const int cs = ((sc - (sr >> 1)) & 3) * 16;  // swizzled global byte offset
  const int srow0 = wave * 32 + sr;
  // reader: frag chunk g at row -> slot (g + (row>>1))&3; row>>1 mod 4 == fr>>1
  const int fr = lane & 15;
  const int g = lane >> 4;
  const int fco = ((g + (fr >> 1)) & 3) * 8;  // swizzled LDS element offset

  const int kiters = K >> 5;
  for (int kt = 0; kt < kiters; ++kt) {
    const int k0 = kt << 5;
    __syncthreads();
    {
      const char* gA0 = (const char*)A + ((size_t)(m0 + srow0) * K + k0) * 2 + cs;
      const char* gA1 = gA0 + (size_t)16 * K * 2;
      const char* gB0 = (const char*)B + ((size_t)(n0 + srow0) * K + k0) * 2 + cs;
      const char* gB1 = gB0 + (size_t)16 * K * 2;
      __builtin_amdgcn_global_load_lds(
          (__attribute__((address_space(1))) void*)gA0,
          (__attribute__((address_space(3))) void*)(As + (wave * 2 + 0) * 512), 16, 0, 0);
      __builtin_amdgcn_global_load_lds(
          (__attribute__((address_space(1))) void*)gA1,
          (__attribute__((address_space(3))) void*)(As + (wave * 2 + 1) * 512), 16, 0, 0);
      __builtin_amdgcn_global_load_lds(
          (__attribute__((address_space(1))) void*)gB0,
          (__attribute__((address_space(3))) void*)(Bs + (wave * 2 + 0) * 512), 16, 0, 0);
      __builtin_amdgcn_global_load_lds(
          (__attribute__((address_space(1))) void*)gB1,
          (__attribute__((address_space(3))) void*)(Bs + (wave * 2 + 1) * 512), 16, 0, 0);
    }
    __syncthreads();
    bf16x8 aF[4], bF[4];
#pragma unroll
    for (int mi = 0; mi < 4; ++mi)
      __builtin_memcpy(&aF[mi], &As[(wm + mi * 16 + fr) * 32 + fco], 16);
#pragma unroll
    for (int ni = 0; ni < 4; ++ni)
      __builtin_memcpy(&bF[ni], &Bs[(wn + ni * 16 + fr) * 32 + fco], 16);
#pragma unroll
    for (int mi = 0; mi < 4; ++mi)
#pragma unroll
      for (int ni = 0; ni < 4; ++ni)
        acc[mi][ni] = __builtin_amdgcn_mfma_f32_16x16x32_bf16(aF[mi], bF[ni], acc[mi][ni], 0, 0, 0);
  }
  const int rq = (lane >> 4) * 4;
  const int cq = lane & 15;
#pragma unroll
  for (int mi = 0; mi < 4; ++mi) {
#pragma unroll
    for (int ni = 0; ni < 4; ++ni) {
      int col = n0 + wn + ni * 16 + cq;
      float bs = bias[col];
#pragma unroll
      for (int i = 0; i < 4; ++i) {
        int row = m0 + wm + mi * 16 + rq + i;
        float v = acc[mi][ni][i] + bs;
        if (OUT_BF16)
          ((u16*)Cv)[(size_t)row * N + col] = f2b(v);
        else
          ((float*)Cv)[(size_t)row * N + col] = v;
      }
    }
  }
}

// ---------------- RoPE on q,k (q pre-scaled by 1/sqrt(d)) ----------------
__global__ __launch_bounds__(256) void rope_reshape(
    const u16* __restrict__ qkv, u16* __restrict__ qh, u16* __restrict__ kh) {
  int idx = blockIdx.x * 256 + threadIdx.x;
  int i = idx & 63;
  int h = (idx >> 6) & 15;
  int l = (idx >> 10) & 2047;
  int b = idx >> 21;
  const u16* row = qkv + ((size_t)(b * 2048 + l)) * 6144;
  int off = h * 128 + i;
  float q1 = b2f(row[off]), q2 = b2f(row[off + 64]);
  float k1 = b2f(row[2048 + off]), k2 = b2f(row[2048 + off + 64]);
  float inv = exp2f(-(float)i * 0.20762050593046869f);
  float ang = (float)l * inv;
  float s, c;
  sincosf(ang, &s, &c);
  size_t o = ((size_t)(b * 16 + h) * 2048 + l) * 128;
  const float qs = 0.08838834764831845f;
  qh[o + i]      = f2b((q1 * c - q2 * s) * qs);
  qh[o + 64 + i] = f2b((q2 * c + q1 * s) * qs);
  kh[o + i]      = f2b(k1 * c - k2 * s);
  kh[o + 64 + i] = f2b(k2 * c + k1 * s);
}

// ---------------- V transpose: qkv v-slice -> vhT[(b,h), d, L] ----------------
__global__ __launch_bounds__(256) void transpose_v(
    const u16* __restrict__ qkv, u16* __restrict__ vhT) {
  __shared__ u16 Ts[64 * 65];
  const int tid = threadIdx.x;
  const int lt = blockIdx.x;
  const int dh = blockIdx.y;
  const int bh = blockIdx.z;
  const int b = bh >> 4, h = bh & 15;
  const int l0 = lt * 64, d0 = dh * 64;
#pragma unroll
  for (int it = 0; it < 16; ++it) {
    int idx = it * 256 + tid;
    int l = idx >> 6, d = idx & 63;
    Ts[l * 65 + d] =
        qkv[((size_t)(b * 2048 + l0 + l)) * 6144 + 4096 + h * 128 + d0 + d];
  }
  __syncthreads();
#pragma unroll
  for (int it = 0; it < 16; ++it) {
    int idx = it * 256 + tid;
    int d = idx >> 6, l = idx & 63;
    vhT[((size_t)bh * 128 + d0 + d) * 2048 + l0 + l] = Ts[l * 65 + d];
  }
}

// ---------------- causal flash attention, S^T orientation ----------------
// K/V staged via global_load_lds with XOR-swizzled layout (slot = chunk ^ (row&7)),
// removing the register round-trip and LDS bank conflicts without padding.
__global__ __launch_bounds__(256, 2) void attn_flash(
    const u16* __restrict__ qh, const u16* __restrict__ kh,
    const u16* __restrict__ vhT, u16* __restrict__ oh) {
  __shared__ __align__(16) u16 Ks[64 * 128];   // [kpos][d], swizzled 16B chunks
  __shared__ __align__(16) u16 Vt[128 * 64];   // [d][kpos], swizzled 16B chunks
  __shared__ __align__(16) u16 Ps[128 * 72];   // [q_local][kpos], padded
  const int tid = threadIdx.x;
  const int lane = tid & 63;
  const int w = tid >> 6;
  const int cq = lane & 15;
  const int g = lane >> 4;
  const int p = blockIdx.x;
  const int bh = blockIdx.y;
  const int b = bh >> 4, h = bh & 15;
  const int ktiles = 32 - p;
  int q0s[2];
  q0s[0] = p * 64;
  q0s[1] = (31 - p) * 64;

  bf16x8 qf[2][4];
#pragma unroll
  for (int s = 0; s < 2; ++s) {
    const u16* qp = qh + ((size_t)bh * 2048 + q0s[s] + w * 16 + cq) * 128 + g * 8;
#pragma unroll
    for (int ks = 0; ks < 4; ++ks)
      __builtin_memcpy(&qf[s][ks], qp + ks * 32, 16);
  }

  f32x4 o[2][8] = {};
  float mrow[2] = {-1e30f, -1e30f};
  float lrow[2] = {0.0f, 0.0f};

  // staging lane geometry (wave-invariant parts)
  const int krl = lane >> 4;           // K: row within 4-row chunk
  const int kcl = lane & 15;           // K: slot within row (16 chunks)
  const int vrl = lane >> 3;           // V: row within 8-row chunk
  const int vcl = lane & 7;            // V: slot within row (8 chunks)

  for (int kt = 0; kt < ktiles; ++kt) {
    __syncthreads();
    {
      const size_t kvb = (size_t)bh * 2048 + (size_t)kt * 64;
#pragma unroll
      for (int i = 0; i < 4; ++i) {
        int row = w * 16 + i * 4 + krl;
        int cgl = kcl ^ (row & 7);
        const char* src = (const char*)(kh + (kvb + row) * 128 + cgl * 8);
        __builtin_amdgcn_global_load_lds(
            (__attribute__((address_space(1))) void*)src,
            (__attribute__((address_space(3))) void*)(Ks + (w * 16 + i * 4) * 128),
            16, 0, 0);
      }
#pragma unroll
      for (int i = 0; i < 4; ++i) {
        int row = w * 32 + i * 8 + vrl;
        int cgl = vcl ^ (row & 7);
        const char* src =
            (const char*)(vhT + ((size_t)bh * 128 + row) * 2048 + kt * 64 + cgl * 8);
        __builtin_amdgcn_global_load_lds(
            (__attribute__((address_space(1))) void*)src,
            (__attribute__((address_space(3))) void*)(Vt + (w * 32 + i * 8) * 64),
            16, 0, 0);
      }
    }
    __syncthreads();

    const bool nA = (kt <= p);
    f32x4 S[4][2] = {};
#pragma unroll
    for (int ks = 0; ks < 4; ++ks) {
#pragma unroll
      for (int mt = 0; mt < 4; ++mt) {
        bf16x8 kf;
        int slot = (ks * 4 + g) ^ (cq & 7);
        __builtin_memcpy(&kf, &Ks[(mt * 16 + cq) * 128 + slot * 8], 16);
        if (nA)
          S[mt][0] = __builtin_amdgcn_mfma_f32_16x16x32_bf16(kf, qf[0][ks], S[mt][0], 0, 0, 0);
        S[mt][1] = __builtin_amdgcn_mfma_f32_16x16x32_bf16(kf, qf[1][ks], S[mt][1], 0, 0, 0);
      }
    }

#pragma unroll
    for (int s = 0; s < 2; ++s) {
      if (s == 0 && !nA) continue;
      const int dtile = s ? (ktiles - 1) : p;
      if (kt == dtile) {
        const int qg = q0s[s] + w * 16 + cq;
#pragma unroll
        for (int mt = 0; mt < 4; ++mt)
#pragma unroll
          for (int i = 0; i < 4; ++i)
            if (kt * 64 + mt * 16 + g * 4 + i > qg) S[mt][s][i] = -1e30f;
      }
      float mx = S[0][s][0];
#pragma unroll
      for (int mt = 0; mt < 4; ++mt)
#pragma unroll
        for (int i = 0; i < 4; ++i) mx = fmaxf(mx, S[mt][s][i]);
      mx = fmaxf(mx, __shfl_xor(mx, 16));
      mx = fmaxf(mx, __shfl_xor(mx, 32));
      float mnew = fmaxf(mrow[s], mx);
      float al = __expf(mrow[s] - mnew);
      mrow[s] = mnew;
      float rs = 0.0f;
#pragma unroll
      for (int mt = 0; mt < 4; ++mt) {
        float e0 = __expf(S[mt][s][0] - mnew);
        float e1 = __expf(S[mt][s][1] - mnew);
        float e2 = __expf(S[mt][s][2] - mnew);
        float e3 = __expf(S[mt][s][3] - mnew);
        rs += (e0 + e1) + (e2 + e3);
        ushort4 pk;
        pk.x = f2b(e0); pk.y = f2b(e1); pk.z = f2b(e2); pk.w = f2b(e3);
        *(ushort4*)&Ps[(s * 64 + w * 16 + cq) * 72 + mt * 16 + g * 4] = pk;
      }
      rs += __shfl_xor(rs, 16);
      rs += __shfl_xor(rs, 32);
      lrow[s] = lrow[s] * al + rs;
#pragma unroll
      for (int dmt = 0; dmt < 8; ++dmt) {
        o[s][dmt][0] *= al; o[s][dmt][1] *= al;
        o[s][dmt][2] *= al; o[s][dmt][3] *= al;
      }
    }

#pragma unroll
    for (int ks = 0; ks < 2; ++ks) {
      bf16x8 pf0, pf1;
      if (nA) __builtin_memcpy(&pf0, &Ps[(w * 16 + cq) * 72 + ks * 32 + g * 8], 16);
      __builtin_memcpy(&pf1, &Ps[(64 + w * 16 + cq) * 72 + ks * 32 + g * 8], 16);
#pragma unroll
      for (int dmt = 0; dmt < 8; ++dmt) {
        bf16x8 vf;
        int slot = (ks * 4 + g) ^ (cq & 7);
        __builtin_memcpy(&vf, &Vt[(dmt * 16 + cq) * 64 + slot * 8], 16);
        if (nA)
          o[0][dmt] = __builtin_amdgcn_mfma_f32_16x16x32_bf16(vf, pf0, o[0][dmt], 0, 0, 0);
        o[1][dmt] = __builtin_amdgcn_mfma_f32_16x16x32_bf16(vf, pf1, o[1][dmt], 0, 0, 0);
      }
    }
  }

#pragma unroll
  for (int s = 0; s < 2; ++s) {
    float inv = 1.0f / lrow[s];
    int qg = q0s[s] + w * 16 + cq;
    size_t base = ((size_t)(b * 2048 + qg)) * 2048 + h * 128;
#pragma unroll
    for (int dmt = 0; dmt < 8; ++dmt) {
      ushort4 t;
      t.x = f2b(o[s][dmt][0] * inv);
      t.y = f2b(o[s][dmt][1] * inv);
      t.z = f2b(o[s][dmt][2] * inv);
      t.w = f2b(o[s][dmt][3] * inv);
      *(ushort4*)(oh + base + dmt * 16 + g * 4) = t;
    }
  }
}

extern "C" void kernel_launch(void* const* d_in, const int* in_sizes, int n_in,
                              void* d_out, int out_size, void* d_ws, size_t ws_size,
                              hipStream_t stream) {
  (void)in_sizes; (void)n_in; (void)out_size; (void)ws_size;
  const float* query = (const float*)d_in[0];
  const float* W_qkv = (const float*)d_in[1];
  const float* b_qkv = (const float*)d_in[2];
  const float* W_out = (const float*)d_in[3];
  const float* b_out = (const float*)d_in[4];
  float* out = (float*)d_out;
  char* ws = (char*)d_ws;

  u16* Abf  = (u16*)(ws + 0);                    // 16 MB  query bf16
  u16* W1bf = (u16*)(ws + (size_t)16777216);     // 24 MB  W_qkv bf16
  u16* W2bf = (u16*)(ws + (size_t)41943040);     //  8 MB  W_out bf16
  u16* QKV  = (u16*)(ws + (size_t)50331648);     // 48 MB  qkv bf16
  u16* qhp  = (u16*)(ws + (size_t)100663296);    // 16 MB  (B*H,L,128), pre-scaled
  u16* khp  = (u16*)(ws + (size_t)117440512);    // 16 MB  (B*H,L,128)
  u16* vhT  = (u16*)(ws + (size_t)134217728);    // 16 MB  (B*H,128,L)
  u16* ohp  = (u16*)(ws + (size_t)150994944);    // 16 MB  attn out (B,L,2048)

  convert_f32_bf16<<<8192, 256, 0, stream>>>((const float4*)query, (ushort4*)Abf, 2097152);
  convert_f32_bf16<<<12288, 256, 0, stream>>>((const float4*)W_qkv, (ushort4*)W1bf, 3145728);
  convert_f32_bf16<<<4096, 256, 0, stream>>>((const float4*)W_out, (ushort4*)W2bf, 1048576);
  gemm_bt<1><<<dim3(48, 32), 256, 0, stream>>>(Abf, W1bf, b_qkv, (void*)QKV, 4096, 6144, 2048);
  rope_reshape<<<16384, 256, 0, stream>>>(QKV, qhp, khp);
  transpose_v<<<dim3(32, 2, 32), 256, 0, stream>>>(QKV, vhT);
  attn_flash<<<dim3(16, 32), 256, 0, stream>>>(qhp, khp, vhT, ohp);
  gemm_bt<0><<<dim3(16, 32), 256, 0, stream>>>(ohp, W2bf, b_out, (void*)out, 4096, 2048, 2048);
}

// Round 4
// 386.245 us; speedup vs baseline: 1.4759x; 1.0710x over previous
//
#include <hip/hip_runtime.h>

typedef unsigned short u16;
typedef unsigned int u32;
typedef __bf16 bf16x8 __attribute__((ext_vector_type(8)));
typedef float f32x4 __attribute__((ext_vector_type(4)));

__device__ __forceinline__ u16 f2b(float f) {
  u32 u = __float_as_uint(f);
  u32 r = (u + 0x7fffu + ((u >> 16) & 1u)) >> 16;
  return (u16)r;
}
__device__ __forceinline__ float b2f(u16 v) {
  return __uint_as_float(((u32)v) << 16);
}

// ---------------- fused fp32 -> bf16 cast of query, W_qkv, W_out ----------------
// Destinations are contiguous in ws (Abf | W1bf | W2bf), so one linear index.
__global__ __launch_bounds__(256) void convert_all(
    const float4* __restrict__ q, const float4* __restrict__ w1,
    const float4* __restrict__ w2, ushort4* __restrict__ out) {
  int i = blockIdx.x * 256 + threadIdx.x;  // < 6291456
  float4 f;
  if (i < 2097152) f = q[i];
  else if (i < 5242880) f = w1[i - 2097152];
  else f = w2[i - 5242880];
  ushort4 o;
  o.x = f2b(f.x); o.y = f2b(f.y); o.z = f2b(f.z); o.w = f2b(f.w);
  out[i] = o;
}

// ---------------- GEMM: C[M,N] = A[M,K] * B[N,K]^T + bias ----------------
// 128x128 tile, BK=64 (halves barrier count vs BK=32; 32 KB LDS keeps occupancy).
// XOR-swizzled LDS: 128B rows, slot = chunk ^ (row&7); staging chunk select is
// the lane-only constant (lane&7)^(lane>>3). 8 lanes per 4-bank window = the
// 8-phase wave64 b128 minimum -> conflict-free.
template <int OUT_BF16>
__global__ __launch_bounds__(256) void gemm_bt(
    const u16* __restrict__ A, const u16* __restrict__ B,
    const float* __restrict__ bias, void* __restrict__ Cv,
    int M, int N, int K) {
  __shared__ __align__(16) u16 As[128 * 64];
  __shared__ __align__(16) u16 Bs[128 * 64];
  const int tid = threadIdx.x;
  const int lane = tid & 63;
  const int wave = tid >> 6;
  const int m0 = blockIdx.y * 128;
  const int n0 = blockIdx.x * 128;
  const int wm = (wave & 1) * 64;
  const int wn = (wave >> 1) * 64;
  f32x4 acc[4][4] = {};

  const int srow = wave * 32 + (lane >> 3);          // staging row (instr adds i*8)
  const int scb = ((lane & 7) ^ (lane >> 3)) * 16;   // swizzled global byte offset
  const int fr = lane & 15;
  const int g = lane >> 4;

  const int kiters = K >> 6;
  for (int kt = 0; kt < kiters; ++kt) {
    const int k0 = kt << 6;
    __syncthreads();
    {
      const char* gA = (const char*)A + ((size_t)(m0 + srow) * K + k0) * 2 + scb;
      const char* gB = (const char*)B + ((size_t)(n0 + srow) * K + k0) * 2 + scb;
#pragma unroll
      for (int i = 0; i < 4; ++i) {
        __builtin_amdgcn_global_load_lds(
            (__attribute__((address_space(1))) void*)(gA + (size_t)i * 8 * K * 2),
            (__attribute__((address_space(3))) void*)(As + (wave * 32 + i * 8) * 64),
            16, 0, 0);
        __builtin_amdgcn_global_load_lds(
            (__attribute__((address_space(1))) void*)(gB + (size_t)i * 8 * K * 2),
            (__attribute__((address_space(3))) void*)(Bs + (wave * 32 + i * 8) * 64),
            16, 0, 0);
      }
    }
    __syncthreads();
#pragma unroll
    for (int ks = 0; ks < 2; ++ks) {
      const int so = ((ks * 4 + g) ^ (fr & 7)) * 8;
      bf16x8 aF[4], bF[4];
#pragma unroll
      for (int mi = 0; mi < 4; ++mi)
        __builtin_memcpy(&aF[mi], &As[(wm + mi * 16 + fr) * 64 + so], 16);
#pragma unroll
      for (int ni = 0; ni < 4; ++ni)
        __builtin_memcpy(&bF[ni], &Bs[(wn + ni * 16 + fr) * 64 + so], 16);
#pragma unroll
      for (int mi = 0; mi < 4; ++mi)
#pragma unroll
        for (int ni = 0; ni < 4; ++ni)
          acc[mi][ni] = __builtin_amdgcn_mfma_f32_16x16x32_bf16(aF[mi], bF[ni], acc[mi][ni], 0, 0, 0);
    }
  }
  const int rq = (lane >> 4) * 4;
  const int cq = lane & 15;
#pragma unroll
  for (int mi = 0; mi < 4; ++mi) {
#pragma unroll
    for (int ni = 0; ni < 4; ++ni) {
      int col = n0 + wn + ni * 16 + cq;
      float bs = bias[col];
#pragma unroll
      for (int i = 0; i < 4; ++i) {
        int row = m0 + wm + mi * 16 + rq + i;
        float v = acc[mi][ni][i] + bs;
        if (OUT_BF16)
          ((u16*)Cv)[(size_t)row * N + col] = f2b(v);
        else
          ((float*)Cv)[(size_t)row * N + col] = v;
      }
    }
  }
}

// ---------------- RoPE on q,k (q pre-scaled by 1/sqrt(d)) ----------------
__global__ __launch_bounds__(256) void rope_reshape(
    const u16* __restrict__ qkv, u16* __restrict__ qh, u16* __restrict__ kh) {
  int idx = blockIdx.x * 256 + threadIdx.x;
  int i = idx & 63;
  int h = (idx >> 6) & 15;
  int l = (idx >> 10) & 2047;
  int b = idx >> 21;
  const u16* row = qkv + ((size_t)(b * 2048 + l)) * 6144;
  int off = h * 128 + i;
  float q1 = b2f(row[off]), q2 = b2f(row[off + 64]);
  float k1 = b2f(row[2048 + off]), k2 = b2f(row[2048 + off + 64]);
  float inv = exp2f(-(float)i * 0.20762050593046869f);
  float ang = (float)l * inv;
  float s, c;
  sincosf(ang, &s, &c);
  size_t o = ((size_t)(b * 16 + h) * 2048 + l) * 128;
  const float qs = 0.08838834764831845f;
  qh[o + i]      = f2b((q1 * c - q2 * s) * qs);
  qh[o + 64 + i] = f2b((q2 * c + q1 * s) * qs);
  kh[o + i]      = f2b(k1 * c - k2 * s);
  kh[o + 64 + i] = f2b(k2 * c + k1 * s);
}

// ---------------- V transpose: qkv v-slice -> vhT[(b,h), d, L] ----------------
__global__ __launch_bounds__(256) void transpose_v(
    const u16* __restrict__ qkv, u16* __restrict__ vhT) {
  __shared__ u16 Ts[64 * 65];
  const int tid = threadIdx.x;
  const int lt = blockIdx.x;
  const int dh = blockIdx.y;
  const int bh = blockIdx.z;
  const int b = bh >> 4, h = bh & 15;
  const int l0 = lt * 64, d0 = dh * 64;
#pragma unroll
  for (int it = 0; it < 16; ++it) {
    int idx = it * 256 + tid;
    int l = idx >> 6, d = idx & 63;
    Ts[l * 65 + d] =
        qkv[((size_t)(b * 2048 + l0 + l)) * 6144 + 4096 + h * 128 + d0 + d];
  }
  __syncthreads();
#pragma unroll
  for (int it = 0; it < 16; ++it) {
    int idx = it * 256 + tid;
    int d = idx >> 6, l = idx & 63;
    vhT[((size_t)bh * 128 + d0 + d) * 2048 + l0 + l] = Ts[l * 65 + d];
  }
}

// ---------------- causal flash attention, S^T orientation ----------------
__global__ __launch_bounds__(256, 2) void attn_flash(
    const u16* __restrict__ qh, const u16* __restrict__ kh,
    const u16* __restrict__ vhT, u16* __restrict__ oh) {
  __shared__ __align__(16) u16 Ks[64 * 128];
  __shared__ __align__(16) u16 Vt[128 * 64];
  __shared__ __align__(16) u16 Ps[128 * 72];
  const int tid = threadIdx.x;
  const int lane = tid & 63;
  const int w = tid >> 6;
  const int cq = lane & 15;
  const int g = lane >> 4;
  const int p = blockIdx.x;
  const int bh = blockIdx.y;
  const int b = bh >> 4, h = bh & 15;
  const int ktiles = 32 - p;
  int q0s[2];
  q0s[0] = p * 64;
  q0s[1] = (31 - p) * 64;

  bf16x8 qf[2][4];
#pragma unroll
  for (int s = 0; s < 2; ++s) {
    const u16* qp = qh + ((size_t)bh * 2048 + q0s[s] + w * 16 + cq) * 128 + g * 8;
#pragma unroll
    for (int ks = 0; ks < 4; ++ks)
      __builtin_memcpy(&qf[s][ks], qp + ks * 32, 16);
  }

  f32x4 o[2][8] = {};
  float mrow[2] = {-1e30f, -1e30f};
  float lrow[2] = {0.0f, 0.0f};

  const int krl = lane >> 4;
  const int kcl = lane & 15;
  const int vrl = lane >> 3;
  const int vcl = lane & 7;

  for (int kt = 0; kt < ktiles; ++kt) {
    __syncthreads();
    {
      const size_t kvb = (size_t)bh * 2048 + (size_t)kt * 64;
#pragma unroll
      for (int i = 0; i < 4; ++i) {
        int row = w * 16 + i * 4 + krl;
        int cgl = kcl ^ (row & 7);
        const char* src = (const char*)(kh + (kvb + row) * 128 + cgl * 8);
        __builtin_amdgcn_global_load_lds(
            (__attribute__((address_space(1))) void*)src,
            (__attribute__((address_space(3))) void*)(Ks + (w * 16 + i * 4) * 128),
            16, 0, 0);
      }
#pragma unroll
      for (int i = 0; i < 4; ++i) {
        int row = w * 32 + i * 8 + vrl;
        int cgl = vcl ^ (row & 7);
        const char* src =
            (const char*)(vhT + ((size_t)bh * 128 + row) * 2048 + kt * 64 + cgl * 8);
        __builtin_amdgcn_global_load_lds(
            (__attribute__((address_space(1))) void*)src,
            (__attribute__((address_space(3))) void*)(Vt + (w * 32 + i * 8) * 64),
            16, 0, 0);
      }
    }
    __syncthreads();

    const bool nA = (kt <= p);
    f32x4 S[4][2] = {};
#pragma unroll
    for (int ks = 0; ks < 4; ++ks) {
#pragma unroll
      for (int mt = 0; mt < 4; ++mt) {
        bf16x8 kf;
        int slot = (ks * 4 + g) ^ (cq & 7);
        __builtin_memcpy(&kf, &Ks[(mt * 16 + cq) * 128 + slot * 8], 16);
        if (nA)
          S[mt][0] = __builtin_amdgcn_mfma_f32_16x16x32_bf16(kf, qf[0][ks], S[mt][0], 0, 0, 0);
        S[mt][1] = __builtin_amdgcn_mfma_f32_16x16x32_bf16(kf, qf[1][ks], S[mt][1], 0, 0, 0);
      }
    }

#pragma unroll
    for (int s = 0; s < 2; ++s) {
      if (s == 0 && !nA) continue;
      const int dtile = s ? (ktiles - 1) : p;
      if (kt == dtile) {
        const int qg = q0s[s] + w * 16 + cq;
#pragma unroll
        for (int mt = 0; mt < 4; ++mt)
#pragma unroll
          for (int i = 0; i < 4; ++i)
            if (kt * 64 + mt * 16 + g * 4 + i > qg) S[mt][s][i] = -1e30f;
      }
      float mx = S[0][s][0];
#pragma unroll
      for (int mt = 0; mt < 4; ++mt)
#pragma unroll
        for (int i = 0; i < 4; ++i) mx = fmaxf(mx, S[mt][s][i]);
      mx = fmaxf(mx, __shfl_xor(mx, 16));
      mx = fmaxf(mx, __shfl_xor(mx, 32));
      float mnew = fmaxf(mrow[s], mx);
      float al = __expf(mrow[s] - mnew);
      mrow[s] = mnew;
      float rs = 0.0f;
#pragma unroll
      for (int mt = 0; mt < 4; ++mt) {
        float e0 = __expf(S[mt][s][0] - mnew);
        float e1 = __expf(S[mt][s][1] - mnew);
        float e2 = __expf(S[mt][s][2] - mnew);
        float e3 = __expf(S[mt][s][3] - mnew);
        rs += (e0 + e1) + (e2 + e3);
        ushort4 pk;
        pk.x = f2b(e0); pk.y = f2b(e1); pk.z = f2b(e2); pk.w = f2b(e3);
        *(ushort4*)&Ps[(s * 64 + w * 16 + cq) * 72 + mt * 16 + g * 4] = pk;
      }
      rs += __shfl_xor(rs, 16);
      rs += __shfl_xor(rs, 32);
      lrow[s] = lrow[s] * al + rs;
#pragma unroll
      for (int dmt = 0; dmt < 8; ++dmt) {
        o[s][dmt][0] *= al; o[s][dmt][1] *= al;
        o[s][dmt][2] *= al; o[s][dmt][3] *= al;
      }
    }

#pragma unroll
    for (int ks = 0; ks < 2; ++ks) {
      bf16x8 pf0, pf1;
      if (nA) __builtin_memcpy(&pf0, &Ps[(w * 16 + cq) * 72 + ks * 32 + g * 8], 16);
      __builtin_memcpy(&pf1, &Ps[(64 + w * 16 + cq) * 72 + ks * 32 + g * 8], 16);
#pragma unroll
      for (int dmt = 0; dmt < 8; ++dmt) {
        bf16x8 vf;
        int slot = (ks * 4 + g) ^ (cq & 7);
        __builtin_memcpy(&vf, &Vt[(dmt * 16 + cq) * 64 + slot * 8], 16);
        if (nA)
          o[0][dmt] = __builtin_amdgcn_mfma_f32_16x16x32_bf16(vf, pf0, o[0][dmt], 0, 0, 0);
        o[1][dmt] = __builtin_amdgcn_mfma_f32_16x16x32_bf16(vf, pf1, o[1][dmt], 0, 0, 0);
      }
    }
  }

#pragma unroll
  for (int s = 0; s < 2; ++s) {
    float inv = 1.0f / lrow[s];
    int qg = q0s[s] + w * 16 + cq;
    size_t base = ((size_t)(b * 2048 + qg)) * 2048 + h * 128;
#pragma unroll
    for (int dmt = 0; dmt < 8; ++dmt) {
      ushort4 t;
      t.x = f2b(o[s][dmt][0] * inv);
      t.y = f2b(o[s][dmt][1] * inv);
      t.z = f2b(o[s][dmt][2] * inv);
      t.w = f2b(o[s][dmt][3] * inv);
      *(ushort4*)(oh + base + dmt * 16 + g * 4) = t;
    }
  }
}

extern "C" void kernel_launch(void* const* d_in, const int* in_sizes, int n_in,
                              void* d_out, int out_size, void* d_ws, size_t ws_size,
                              hipStream_t stream) {
  (void)in_sizes; (void)n_in; (void)out_size; (void)ws_size;
  const float* query = (const float*)d_in[0];
  const float* W_qkv = (const float*)d_in[1];
  const float* b_qkv = (const float*)d_in[2];
  const float* W_out = (const float*)d_in[3];
  const float* b_out = (const float*)d_in[4];
  float* out = (float*)d_out;
  char* ws = (char*)d_ws;

  u16* Abf  = (u16*)(ws + 0);                    // 16 MB  query bf16
  u16* W1bf = (u16*)(ws + (size_t)16777216);     // 24 MB  W_qkv bf16
  u16* W2bf = (u16*)(ws + (size_t)41943040);     //  8 MB  W_out bf16
  u16* QKV  = (u16*)(ws + (size_t)50331648);     // 48 MB  qkv bf16
  u16* qhp  = (u16*)(ws + (size_t)100663296);    // 16 MB  (B*H,L,128), pre-scaled
  u16* khp  = (u16*)(ws + (size_t)117440512);    // 16 MB  (B*H,L,128)
  u16* vhT  = (u16*)(ws + (size_t)134217728);    // 16 MB  (B*H,128,L)
  u16* ohp  = (u16*)(ws + (size_t)150994944);    // 16 MB  attn out (B,L,2048)

  convert_all<<<24576, 256, 0, stream>>>((const float4*)query, (const float4*)W_qkv,
                                         (const float4*)W_out, (ushort4*)ws);
  gemm_bt<1><<<dim3(48, 32), 256, 0, stream>>>(Abf, W1bf, b_qkv, (void*)QKV, 4096, 6144, 2048);
  rope_reshape<<<16384, 256, 0, stream>>>(QKV, qhp, khp);
  transpose_v<<<dim3(32, 2, 32), 256, 0, stream>>>(QKV, vhT);
  attn_flash<<<dim3(16, 32), 256, 0, stream>>>(qhp, khp, vhT, ohp);
  gemm_bt<0><<<dim3(16, 32), 256, 0, stream>>>(ohp, W2bf, b_out, (void*)out, 4096, 2048, 2048);
}

// Round 5
// 380.542 us; speedup vs baseline: 1.4980x; 1.0150x over previous
//
#include <hip/hip_runtime.h>

typedef unsigned short u16;
typedef unsigned int u32;
typedef __bf16 bf16x8 __attribute__((ext_vector_type(8)));
typedef float f32x4 __attribute__((ext_vector_type(4)));

__device__ __forceinline__ u16 f2b(float f) {
  u32 u = __float_as_uint(f);
  u32 r = (u + 0x7fffu + ((u >> 16) & 1u)) >> 16;
  return (u16)r;
}
__device__ __forceinline__ float b2f(u16 v) {
  return __uint_as_float(((u32)v) << 16);
}

// ---------------- fused fp32 -> bf16 cast of query, W_qkv, W_out ----------------
__global__ __launch_bounds__(256) void convert_all(
    const float4* __restrict__ q, const float4* __restrict__ w1,
    const float4* __restrict__ w2, ushort4* __restrict__ out) {
  int i = blockIdx.x * 256 + threadIdx.x;  // < 6291456
  float4 f;
  if (i < 2097152) f = q[i];
  else if (i < 5242880) f = w1[i - 2097152];
  else f = w2[i - 5242880];
  ushort4 o;
  o.x = f2b(f.x); o.y = f2b(f.y); o.z = f2b(f.z); o.w = f2b(f.w);
  out[i] = o;
}

// ---------------- RoPE cos/sin table: tab[l*64+dp] = (cos, sin) ----------------
__global__ __launch_bounds__(256) void rope_tab(float2* __restrict__ tab) {
  int idx = blockIdx.x * 256 + threadIdx.x;  // 131072 = 2048*64
  int l = idx >> 6, dp = idx & 63;
  float inv = exp2f(-(float)dp * 0.20762050593046869f);  // log2(10000)/64
  float ang = (float)l * inv;
  float s, c;
  sincosf(ang, &s, &c);
  tab[idx] = make_float2(c, s);
}

// ---------------- GEMM1 + fused RoPE/head-split/V-transpose epilogue ----------
// C[M=4096, N=6144] = A*W_qkv^T + bias. n-tile t (128 cols) is exactly head
// (t&15) of q (t<16), k (t<32) or v. The C tile is staged through the K-loop's
// 33 KB LDS (stride 129 -> conflict-free for both row-wise RoPE reads and
// column-wise V-transpose reads), then written directly to qh / kh / vhT.
__global__ __launch_bounds__(256) void gemm_qkv(
    const u16* __restrict__ A, const u16* __restrict__ B,
    const float* __restrict__ bias, const float2* __restrict__ tab,
    u16* __restrict__ qh, u16* __restrict__ kh, u16* __restrict__ vhT) {
  __shared__ __align__(16) u16 sh[16512];  // As(8192) | Bs(8192); epi: T stride 129
  u16* As = sh;
  u16* Bs = sh + 8192;
  const int K = 2048;
  const int tid = threadIdx.x;
  const int lane = tid & 63;
  const int wave = tid >> 6;
  const int m0 = blockIdx.y * 128;
  const int n0 = blockIdx.x * 128;
  const int wm = (wave & 1) * 64;
  const int wn = (wave >> 1) * 64;
  f32x4 acc[4][4] = {};

  const int srow = wave * 32 + (lane >> 3);
  const int scb = ((lane & 7) ^ (lane >> 3)) * 16;
  const int fr = lane & 15;
  const int g = lane >> 4;

  for (int kt = 0; kt < 32; ++kt) {
    const int k0 = kt << 6;
    __syncthreads();
    {
      const char* gA = (const char*)A + ((size_t)(m0 + srow) * K + k0) * 2 + scb;
      const char* gB = (const char*)B + ((size_t)(n0 + srow) * K + k0) * 2 + scb;
#pragma unroll
      for (int i = 0; i < 4; ++i) {
        __builtin_amdgcn_global_load_lds(
            (__attribute__((address_space(1))) void*)(gA + (size_t)i * 8 * K * 2),
            (__attribute__((address_space(3))) void*)(As + (wave * 32 + i * 8) * 64),
            16, 0, 0);
        __builtin_amdgcn_global_load_lds(
            (__attribute__((address_space(1))) void*)(gB + (size_t)i * 8 * K * 2),
            (__attribute__((address_space(3))) void*)(Bs + (wave * 32 + i * 8) * 64),
            16, 0, 0);
      }
    }
    __syncthreads();
#pragma unroll
    for (int ks = 0; ks < 2; ++ks) {
      const int so = ((ks * 4 + g) ^ (fr & 7)) * 8;
      bf16x8 aF[4], bF[4];
#pragma unroll
      for (int mi = 0; mi < 4; ++mi)
        __builtin_memcpy(&aF[mi], &As[(wm + mi * 16 + fr) * 64 + so], 16);
#pragma unroll
      for (int ni = 0; ni < 4; ++ni)
        __builtin_memcpy(&bF[ni], &Bs[(wn + ni * 16 + fr) * 64 + so], 16);
#pragma unroll
      for (int mi = 0; mi < 4; ++mi)
#pragma unroll
        for (int ni = 0; ni < 4; ++ni)
          acc[mi][ni] = __builtin_amdgcn_mfma_f32_16x16x32_bf16(aF[mi], bF[ni], acc[mi][ni], 0, 0, 0);
    }
  }

  // ---- epilogue: acc -> LDS tile T (bf16, stride 129) ----
  __syncthreads();  // all waves done reading As/Bs before overwrite
  const int rq = (lane >> 4) * 4;
  const int cq = lane & 15;
#pragma unroll
  for (int mi = 0; mi < 4; ++mi) {
#pragma unroll
    for (int ni = 0; ni < 4; ++ni) {
      int c = wn + ni * 16 + cq;
      float bs = bias[n0 + c];
#pragma unroll
      for (int i = 0; i < 4; ++i) {
        int r = wm + mi * 16 + rq + i;
        sh[r * 129 + c] = f2b(acc[mi][ni][i] + bs);
      }
    }
  }
  __syncthreads();

  const int t = n0 >> 7;       // 0..47
  const int h = t & 15;
  const int bq = m0 >> 11;     // batch (M = B*L, 2048 each)
  const int l0 = m0 & 2047;
  const int bh = bq * 16 + h;

  if (t < 32) {
    // q or k head tile: RoPE rows. 128 rows x 64 pairs, 32 iters.
    const float qs = (t < 16) ? 0.08838834764831845f : 1.0f;
    u16* dst = (t < 16) ? qh : kh;
#pragma unroll 4
    for (int it = 0; it < 32; ++it) {
      int idx = it * 256 + tid;
      int l = idx >> 6, dp = idx & 63;
      float2 cs = tab[(size_t)(l0 + l) * 64 + dp];
      float x1 = b2f(sh[l * 129 + dp]);
      float x2 = b2f(sh[l * 129 + dp + 64]);
      size_t o = ((size_t)bh * 2048 + l0 + l) * 128;
      dst[o + dp]      = f2b((x1 * cs.x - x2 * cs.y) * qs);
      dst[o + dp + 64] = f2b((x2 * cs.x + x1 * cs.y) * qs);
    }
  } else {
    // v head tile: transposed store vhT[bh*128+d][l]. 128 d x 64 l-pairs.
#pragma unroll 4
    for (int it = 0; it < 32; ++it) {
      int idx = it * 256 + tid;
      int d = idx >> 6, l2 = (idx & 63) * 2;
      ushort2 t2;
      t2.x = sh[l2 * 129 + d];
      t2.y = sh[(l2 + 1) * 129 + d];
      *(ushort2*)(vhT + ((size_t)bh * 128 + d) * 2048 + l0 + l2) = t2;
    }
  }
}

// ---------------- GEMM2: out[M,N] = A[M,K] * B[N,K]^T + bias (fp32 out) -------
__global__ __launch_bounds__(256) void gemm_bt(
    const u16* __restrict__ A, const u16* __restrict__ B,
    const float* __restrict__ bias, float* __restrict__ C,
    int M, int N, int K) {
  __shared__ __align__(16) u16 As[128 * 64];
  __shared__ __align__(16) u16 Bs[128 * 64];
  const int tid = threadIdx.x;
  const int lane = tid & 63;
  const int wave = tid >> 6;
  const int m0 = blockIdx.y * 128;
  const int n0 = blockIdx.x * 128;
  const int wm = (wave & 1) * 64;
  const int wn = (wave >> 1) * 64;
  f32x4 acc[4][4] = {};

  const int srow = wave * 32 + (lane >> 3);
  const int scb = ((lane & 7) ^ (lane >> 3)) * 16;
  const int fr = lane & 15;
  const int g = lane >> 4;

  const int kiters = K >> 6;
  for (int kt = 0; kt < kiters; ++kt) {
    const int k0 = kt << 6;
    __syncthreads();
    {
      const char* gA = (const char*)A + ((size_t)(m0 + srow) * K + k0) * 2 + scb;
      const char* gB = (const char*)B + ((size_t)(n0 + srow) * K + k0) * 2 + scb;
#pragma unroll
      for (int i = 0; i < 4; ++i) {
        __builtin_amdgcn_global_load_lds(
            (__attribute__((address_space(1))) void*)(gA + (size_t)i * 8 * K * 2),
            (__attribute__((address_space(3))) void*)(As + (wave * 32 + i * 8) * 64),
            16, 0, 0);
        __builtin_amdgcn_global_load_lds(
            (__attribute__((address_space(1))) void*)(gB + (size_t)i * 8 * K * 2),
            (__attribute__((address_space(3))) void*)(Bs + (wave * 32 + i * 8) * 64),
            16, 0, 0);
      }
    }
    __syncthreads();
#pragma unroll
    for (int ks = 0; ks < 2; ++ks) {
      const int so = ((ks * 4 + g) ^ (fr & 7)) * 8;
      bf16x8 aF[4], bF[4];
#pragma unroll
      for (int mi = 0; mi < 4; ++mi)
        __builtin_memcpy(&aF[mi], &As[(wm + mi * 16 + fr) * 64 + so], 16);
#pragma unroll
      for (int ni = 0; ni < 4; ++ni)
        __builtin_memcpy(&bF[ni], &Bs[(wn + ni * 16 + fr) * 64 + so], 16);
#pragma unroll
      for (int mi = 0; mi < 4; ++mi)
#pragma unroll
        for (int ni = 0; ni < 4; ++ni)
          acc[mi][ni] = __builtin_amdgcn_mfma_f32_16x16x32_bf16(aF[mi], bF[ni], acc[mi][ni], 0, 0, 0);
    }
  }
  const int rq = (lane >> 4) * 4;
  const int cq = lane & 15;
#pragma unroll
  for (int mi = 0; mi < 4; ++mi) {
#pragma unroll
    for (int ni = 0; ni < 4; ++ni) {
      int col = n0 + wn + ni * 16 + cq;
      float bs = bias[col];
#pragma unroll
      for (int i = 0; i < 4; ++i) {
        int row = m0 + wm + mi * 16 + rq + i;
        C[(size_t)row * N + col] = acc[mi][ni][i] + bs;
      }
    }
  }
}

// ---------------- causal flash attention, S^T orientation ----------------
__global__ __launch_bounds__(256, 2) void attn_flash(
    const u16* __restrict__ qh, const u16* __restrict__ kh,
    const u16* __restrict__ vhT, u16* __restrict__ oh) {
  __shared__ __align__(16) u16 Ks[64 * 128];
  __shared__ __align__(16) u16 Vt[128 * 64];
  __shared__ __align__(16) u16 Ps[128 * 72];
  const int tid = threadIdx.x;
  const int lane = tid & 63;
  const int w = tid >> 6;
  const int cq = lane & 15;
  const int g = lane >> 4;
  const int p = blockIdx.x;
  const int bh = blockIdx.y;
  const int b = bh >> 4, h = bh & 15;
  const int ktiles = 32 - p;
  int q0s[2];
  q0s[0] = p * 64;
  q0s[1] = (31 - p) * 64;

  bf16x8 qf[2][4];
#pragma unroll
  for (int s = 0; s < 2; ++s) {
    const u16* qp = qh + ((size_t)bh * 2048 + q0s[s] + w * 16 + cq) * 128 + g * 8;
#pragma unroll
    for (int ks = 0; ks < 4; ++ks)
      __builtin_memcpy(&qf[s][ks], qp + ks * 32, 16);
  }

  f32x4 o[2][8] = {};
  float mrow[2] = {-1e30f, -1e30f};
  float lrow[2] = {0.0f, 0.0f};

  const int krl = lane >> 4;
  const int kcl = lane & 15;
  const int vrl = lane >> 3;
  const int vcl = lane & 7;

  for (int kt = 0; kt < ktiles; ++kt) {
    __syncthreads();
    {
      const size_t kvb = (size_t)bh * 2048 + (size_t)kt * 64;
#pragma unroll
      for (int i = 0; i < 4; ++i) {
        int row = w * 16 + i * 4 + krl;
        int cgl = kcl ^ (row & 7);
        const char* src = (const char*)(kh + (kvb + row) * 128 + cgl * 8);
        __builtin_amdgcn_global_load_lds(
            (__attribute__((address_space(1))) void*)src,
            (__attribute__((address_space(3))) void*)(Ks + (w * 16 + i * 4) * 128),
            16, 0, 0);
      }
#pragma unroll
      for (int i = 0; i < 4; ++i) {
        int row = w * 32 + i * 8 + vrl;
        int cgl = vcl ^ (row & 7);
        const char* src =
            (const char*)(vhT + ((size_t)bh * 128 + row) * 2048 + kt * 64 + cgl * 8);
        __builtin_amdgcn_global_load_lds(
            (__attribute__((address_space(1))) void*)src,
            (__attribute__((address_space(3))) void*)(Vt + (w * 32 + i * 8) * 64),
            16, 0, 0);
      }
    }
    __syncthreads();

    const bool nA = (kt <= p);
    f32x4 S[4][2] = {};
#pragma unroll
    for (int ks = 0; ks < 4; ++ks) {
#pragma unroll
      for (int mt = 0; mt < 4; ++mt) {
        bf16x8 kf;
        int slot = (ks * 4 + g) ^ (cq & 7);
        __builtin_memcpy(&kf, &Ks[(mt * 16 + cq) * 128 + slot * 8], 16);
        if (nA)
          S[mt][0] = __builtin_amdgcn_mfma_f32_16x16x32_bf16(kf, qf[0][ks], S[mt][0], 0, 0, 0);
        S[mt][1] = __builtin_amdgcn_mfma_f32_16x16x32_bf16(kf, qf[1][ks], S[mt][1], 0, 0, 0);
      }
    }

#pragma unroll
    for (int s = 0; s < 2; ++s) {
      if (s == 0 && !nA) continue;
      const int dtile = s ? (ktiles - 1) : p;
      if (kt == dtile) {
        const int qg = q0s[s] + w * 16 + cq;
#pragma unroll
        for (int mt = 0; mt < 4; ++mt)
#pragma unroll
          for (int i = 0; i < 4; ++i)
            if (kt * 64 + mt * 16 + g * 4 + i > qg) S[mt][s][i] = -1e30f;
      }
      float mx = S[0][s][0];
#pragma unroll
      for (int mt = 0; mt < 4; ++mt)
#pragma unroll
        for (int i = 0; i < 4; ++i) mx = fmaxf(mx, S[mt][s][i]);
      mx = fmaxf(mx, __shfl_xor(mx, 16));
      mx = fmaxf(mx, __shfl_xor(mx, 32));
      float mnew = fmaxf(mrow[s], mx);
      float al = __expf(mrow[s] - mnew);
      mrow[s] = mnew;
      float rs = 0.0f;
#pragma unroll
      for (int mt = 0; mt < 4; ++mt) {
        float e0 = __expf(S[mt][s][0] - mnew);
        float e1 = __expf(S[mt][s][1] - mnew);
        float e2 = __expf(S[mt][s][2] - mnew);
        float e3 = __expf(S[mt][s][3] - mnew);
        rs += (e0 + e1) + (e2 + e3);
        ushort4 pk;
        pk.x = f2b(e0); pk.y = f2b(e1); pk.z = f2b(e2); pk.w = f2b(e3);
        *(ushort4*)&Ps[(s * 64 + w * 16 + cq) * 72 + mt * 16 + g * 4] = pk;
      }
      rs += __shfl_xor(rs, 16);
      rs += __shfl_xor(rs, 32);
      lrow[s] = lrow[s] * al + rs;
#pragma unroll
      for (int dmt = 0; dmt < 8; ++dmt) {
        o[s][dmt][0] *= al; o[s][dmt][1] *= al;
        o[s][dmt][2] *= al; o[s][dmt][3] *= al;
      }
    }

#pragma unroll
    for (int ks = 0; ks < 2; ++ks) {
      bf16x8 pf0, pf1;
      if (nA) __builtin_memcpy(&pf0, &Ps[(w * 16 + cq) * 72 + ks * 32 + g * 8], 16);
      __builtin_memcpy(&pf1, &Ps[(64 + w * 16 + cq) * 72 + ks * 32 + g * 8], 16);
#pragma unroll
      for (int dmt = 0; dmt < 8; ++dmt) {
        bf16x8 vf;
        int slot = (ks * 4 + g) ^ (cq & 7);
        __builtin_memcpy(&vf, &Vt[(dmt * 16 + cq) * 64 + slot * 8], 16);
        if (nA)
          o[0][dmt] = __builtin_amdgcn_mfma_f32_16x16x32_bf16(vf, pf0, o[0][dmt], 0, 0, 0);
        o[1][dmt] = __builtin_amdgcn_mfma_f32_16x16x32_bf16(vf, pf1, o[1][dmt], 0, 0, 0);
      }
    }
  }

#pragma unroll
  for (int s = 0; s < 2; ++s) {
    float inv = 1.0f / lrow[s];
    int qg = q0s[s] + w * 16 + cq;
    size_t base = ((size_t)(b * 2048 + qg)) * 2048 + h * 128;
#pragma unroll
    for (int dmt = 0; dmt < 8; ++dmt) {
      ushort4 t;
      t.x = f2b(o[s][dmt][0] * inv);
      t.y = f2b(o[s][dmt][1] * inv);
      t.z = f2b(o[s][dmt][2] * inv);
      t.w = f2b(o[s][dmt][3] * inv);
      *(ushort4*)(oh + base + dmt * 16 + g * 4) = t;
    }
  }
}

extern "C" void kernel_launch(void* const* d_in, const int* in_sizes, int n_in,
                              void* d_out, int out_size, void* d_ws, size_t ws_size,
                              hipStream_t stream) {
  (void)in_sizes; (void)n_in; (void)out_size; (void)ws_size;
  const float* query = (const float*)d_in[0];
  const float* W_qkv = (const float*)d_in[1];
  const float* b_qkv = (const float*)d_in[2];
  const float* W_out = (const float*)d_in[3];
  const float* b_out = (const float*)d_in[4];
  float* out = (float*)d_out;
  char* ws = (char*)d_ws;

  u16*    Abf  = (u16*)(ws + 0);                    // 16 MB  query bf16
  u16*    W1bf = (u16*)(ws + (size_t)16777216);     // 24 MB  W_qkv bf16
  u16*    W2bf = (u16*)(ws + (size_t)41943040);     //  8 MB  W_out bf16
  u16*    qhp  = (u16*)(ws + (size_t)50331648);     // 16 MB  (B*H,L,128) pre-scaled
  u16*    khp  = (u16*)(ws + (size_t)67108864);     // 16 MB  (B*H,L,128)
  u16*    vhT  = (u16*)(ws + (size_t)83886080);     // 16 MB  (B*H,128,L)
  u16*    ohp  = (u16*)(ws + (size_t)100663296);    // 16 MB  attn out (B,L,2048)
  float2* tab  = (float2*)(ws + (size_t)117440512); //  1 MB  rope cos/sin

  convert_all<<<24576, 256, 0, stream>>>((const float4*)query, (const float4*)W_qkv,
                                         (const float4*)W_out, (ushort4*)ws);
  rope_tab<<<512, 256, 0, stream>>>(tab);
  gemm_qkv<<<dim3(48, 32), 256, 0, stream>>>(Abf, W1bf, b_qkv, tab, qhp, khp, vhT);
  attn_flash<<<dim3(16, 32), 256, 0, stream>>>(qhp, khp, vhT, ohp);
  gemm_bt<<<dim3(16, 32), 256, 0, stream>>>(ohp, W2bf, b_out, out, 4096, 2048, 2048);
}